// Round 1
// baseline (4267.098 us; speedup 1.0000x reference)
//
#include <hip/hip_runtime.h>

// GCN 2-layer forward, f32 baseline.
// Pipeline: gemm1 -> spmm(atomic) -> gemm2(fused relu+b1) -> spmm(atomic) -> log_softmax(+b2)

// ---------------- GEMM1: Y[M,128] = X[M,256] @ W[256,128] ----------------
__global__ __launch_bounds__(256) void gemm1_k(const float* __restrict__ X,
                                               const float* __restrict__ W,
                                               float* __restrict__ Y, int M) {
  __shared__ float xs[128][64];   // 32 KB  (rows x k-chunk)
  __shared__ float ws[64][128];   // 32 KB  (k-chunk x cols)
  const int tid = threadIdx.x;
  const int bm = blockIdx.x * 128;
  const int rg = tid >> 4;   // 16 row groups of 8 rows
  const int cg = tid & 15;   // 16 col groups of 8 cols
  float acc[8][8];
#pragma unroll
  for (int i = 0; i < 8; ++i)
#pragma unroll
    for (int j = 0; j < 8; ++j) acc[i][j] = 0.f;

  for (int k0 = 0; k0 < 256; k0 += 64) {
    // stage X tile: 128x64 floats = 2048 float4, 8 per thread (coalesced)
#pragma unroll
    for (int i = 0; i < 8; ++i) {
      int idx = tid + i * 256;
      int r = idx >> 4;             // 16 float4 per row
      int kk = (idx & 15) << 2;
      int row = bm + r;
      float4 v = make_float4(0.f, 0.f, 0.f, 0.f);
      if (row < M) v = *(const float4*)&X[(size_t)row * 256 + k0 + kk];
      *(float4*)&xs[r][kk] = v;
    }
    // stage W chunk: 64x128 floats = 2048 float4
#pragma unroll
    for (int i = 0; i < 8; ++i) {
      int idx = tid + i * 256;
      int r = idx >> 5;             // 32 float4 per row
      int c = (idx & 31) << 2;
      *(float4*)&ws[r][c] = *(const float4*)&W[(size_t)(k0 + r) * 128 + c];
    }
    __syncthreads();
#pragma unroll
    for (int k4 = 0; k4 < 64; k4 += 4) {
      float4 xv[8];
#pragma unroll
      for (int r = 0; r < 8; ++r) xv[r] = *(const float4*)&xs[rg * 8 + r][k4];
#pragma unroll
      for (int kk = 0; kk < 4; ++kk) {
        float4 wa = *(const float4*)&ws[k4 + kk][cg * 8];
        float4 wb = *(const float4*)&ws[k4 + kk][cg * 8 + 4];
#pragma unroll
        for (int r = 0; r < 8; ++r) {
          float xx = (&xv[r].x)[kk];
          acc[r][0] = fmaf(xx, wa.x, acc[r][0]);
          acc[r][1] = fmaf(xx, wa.y, acc[r][1]);
          acc[r][2] = fmaf(xx, wa.z, acc[r][2]);
          acc[r][3] = fmaf(xx, wa.w, acc[r][3]);
          acc[r][4] = fmaf(xx, wb.x, acc[r][4]);
          acc[r][5] = fmaf(xx, wb.y, acc[r][5]);
          acc[r][6] = fmaf(xx, wb.z, acc[r][6]);
          acc[r][7] = fmaf(xx, wb.w, acc[r][7]);
        }
      }
    }
    __syncthreads();
  }
#pragma unroll
  for (int r = 0; r < 8; ++r) {
    int row = bm + rg * 8 + r;
    if (row < M) {
      *(float4*)&Y[(size_t)row * 128 + cg * 8] =
          make_float4(acc[r][0], acc[r][1], acc[r][2], acc[r][3]);
      *(float4*)&Y[(size_t)row * 128 + cg * 8 + 4] =
          make_float4(acc[r][4], acc[r][5], acc[r][6], acc[r][7]);
    }
  }
}

// -------- GEMM2: Y[M,64] = relu(H[M,128] + b1) @ W[128,64] (bias fused on load) --------
__global__ __launch_bounds__(256) void gemm2_k(const float* __restrict__ H,
                                               const float* __restrict__ b1,
                                               const float* __restrict__ W,
                                               float* __restrict__ Y, int M) {
  __shared__ float xs[128][64];  // 32 KB
  __shared__ float ws[64][64];   // 16 KB
  const int tid = threadIdx.x;
  const int bm = blockIdx.x * 128;
  const int rg = tid >> 4;   // 16 row groups of 8 rows
  const int cg = tid & 15;   // 16 col groups of 4 cols
  float acc[8][4];
#pragma unroll
  for (int i = 0; i < 8; ++i)
#pragma unroll
    for (int j = 0; j < 4; ++j) acc[i][j] = 0.f;

  for (int k0 = 0; k0 < 128; k0 += 64) {
    // stage H tile with fused bias+relu
#pragma unroll
    for (int i = 0; i < 8; ++i) {
      int idx = tid + i * 256;
      int r = idx >> 4;
      int kk = (idx & 15) << 2;
      int row = bm + r;
      float4 v = make_float4(0.f, 0.f, 0.f, 0.f);
      if (row < M) {
        v = *(const float4*)&H[(size_t)row * 128 + k0 + kk];
        float4 b = *(const float4*)&b1[k0 + kk];
        v.x = fmaxf(v.x + b.x, 0.f);
        v.y = fmaxf(v.y + b.y, 0.f);
        v.z = fmaxf(v.z + b.z, 0.f);
        v.w = fmaxf(v.w + b.w, 0.f);
      }
      *(float4*)&xs[r][kk] = v;
    }
    // stage W chunk: 64x64 = 1024 float4, 4 per thread
#pragma unroll
    for (int i = 0; i < 4; ++i) {
      int idx = tid + i * 256;
      int r = idx >> 4;             // 16 float4 per row
      int c = (idx & 15) << 2;
      *(float4*)&ws[r][c] = *(const float4*)&W[(size_t)(k0 + r) * 64 + c];
    }
    __syncthreads();
#pragma unroll
    for (int k4 = 0; k4 < 64; k4 += 4) {
      float4 xv[8];
#pragma unroll
      for (int r = 0; r < 8; ++r) xv[r] = *(const float4*)&xs[rg * 8 + r][k4];
#pragma unroll
      for (int kk = 0; kk < 4; ++kk) {
        float4 wa = *(const float4*)&ws[k4 + kk][cg * 4];
#pragma unroll
        for (int r = 0; r < 8; ++r) {
          float xx = (&xv[r].x)[kk];
          acc[r][0] = fmaf(xx, wa.x, acc[r][0]);
          acc[r][1] = fmaf(xx, wa.y, acc[r][1]);
          acc[r][2] = fmaf(xx, wa.z, acc[r][2]);
          acc[r][3] = fmaf(xx, wa.w, acc[r][3]);
        }
      }
    }
    __syncthreads();
  }
#pragma unroll
  for (int r = 0; r < 8; ++r) {
    int row = bm + rg * 8 + r;
    if (row < M)
      *(float4*)&Y[(size_t)row * 64 + cg * 4] =
          make_float4(acc[r][0], acc[r][1], acc[r][2], acc[r][3]);
  }
}

// ---------------- SpMM scatter: out[dst[e]] += vals[e] * X[src[e]] ----------------
// LOGQ: log2 of float4-groups per row (C = 4 << LOGQ)
template <int LOGQ>
__global__ __launch_bounds__(256) void spmm_k(const float* __restrict__ vals,
                                              const int* __restrict__ src,
                                              const int* __restrict__ dst,
                                              const float* __restrict__ X,
                                              float* __restrict__ out, int E) {
  long long gid = (long long)blockIdx.x * 256 + threadIdx.x;
  if (gid >= ((long long)E << LOGQ)) return;
  int e = (int)(gid >> LOGQ);
  int g = (int)(gid & ((1 << LOGQ) - 1));
  const int C = 4 << LOGQ;
  float v = vals[e];
  int s = src[e];
  int d = dst[e];
  float4 xv = *(const float4*)&X[(size_t)s * C + g * 4];
  float* o = &out[(size_t)d * C + g * 4];
  atomicAdd(o + 0, v * xv.x);
  atomicAdd(o + 1, v * xv.y);
  atomicAdd(o + 2, v * xv.z);
  atomicAdd(o + 3, v * xv.w);
}

// ---------------- log_softmax over rows of 64, bias fused ----------------
__global__ __launch_bounds__(256) void lsm_k(const float* __restrict__ A,
                                             const float* __restrict__ b2,
                                             float* __restrict__ out, int M) {
  int row = blockIdx.x * 4 + (threadIdx.x >> 6);
  int lane = threadIdx.x & 63;
  if (row >= M) return;
  float v = A[(size_t)row * 64 + lane] + b2[lane];
  float m = v;
#pragma unroll
  for (int o = 32; o > 0; o >>= 1) m = fmaxf(m, __shfl_xor(m, o, 64));
  float e = expf(v - m);
  float s = e;
#pragma unroll
  for (int o = 32; o > 0; o >>= 1) s += __shfl_xor(s, o, 64);
  out[(size_t)row * 64 + lane] = v - m - logf(s);
}

extern "C" void kernel_launch(void* const* d_in, const int* in_sizes, int n_in,
                              void* d_out, int out_size, void* d_ws, size_t ws_size,
                              hipStream_t stream) {
  const float* x    = (const float*)d_in[0];
  const int*   src  = (const int*)  d_in[1];
  const int*   dst  = (const int*)  d_in[2];
  const float* vals = (const float*)d_in[3];
  const float* W1   = (const float*)d_in[4];
  const float* b1   = (const float*)d_in[5];
  const float* W2   = (const float*)d_in[6];
  const float* b2   = (const float*)d_in[7];
  const int M = in_sizes[0] / 256;   // 100000
  const int E = in_sizes[1];         // 1600000

  float* ws   = (float*)d_ws;
  float* xw   = ws;                          // M*128 floats
  float* hacc = ws + (size_t)M * 128;        // M*128 floats
  float* hw   = ws;                          // M*64 (reuses xw, dead after spmm1)
  float* o2   = ws + (size_t)M * 64;         // M*64 (reuses xw upper half)
  float* outf = (float*)d_out;

  const int gb = (M + 127) / 128;

  // zero layer-1 accumulator (d_ws is poisoned, not re-zeroed between replays)
  hipMemsetAsync(hacc, 0, (size_t)M * 128 * sizeof(float), stream);

  gemm1_k<<<gb, 256, 0, stream>>>(x, W1, xw, M);

  {
    long long items = (long long)E << 5;               // E * 32 groups
    int blocks = (int)((items + 255) / 256);
    spmm_k<5><<<blocks, 256, 0, stream>>>(vals, src, dst, xw, hacc, E);
  }

  gemm2_k<<<gb, 256, 0, stream>>>(hacc, b1, W2, hw, M);

  // zero layer-2 accumulator (region overlapped xw; xw is dead now)
  hipMemsetAsync(o2, 0, (size_t)M * 64 * sizeof(float), stream);

  {
    long long items = (long long)E << 4;               // E * 16 groups
    int blocks = (int)((items + 255) / 256);
    spmm_k<4><<<blocks, 256, 0, stream>>>(vals, src, dst, hw, o2, E);
  }

  lsm_k<<<(M + 3) / 4, 256, 0, stream>>>(o2, b2, outf, M);
}

// Round 2
// 587.012 us; speedup vs baseline: 7.2692x; 7.2692x over previous
//
#include <hip/hip_runtime.h>
#include <stdint.h>

// GCN 2-layer forward.
// Pipeline: CSR build (hist/scan/scatter) -> gemm1 -> spmm_csr -> gemm2(fused relu+b1)
//           -> spmm_csr -> log_softmax(+b2)

// ---------------- GEMM1: Y[M,128] = X[M,256] @ W[256,128] ----------------
__global__ __launch_bounds__(256) void gemm1_k(const float* __restrict__ X,
                                               const float* __restrict__ W,
                                               float* __restrict__ Y, int M) {
  __shared__ float xs[128][64];   // 32 KB  (rows x k-chunk)
  __shared__ float ws[64][128];   // 32 KB  (k-chunk x cols)
  const int tid = threadIdx.x;
  const int bm = blockIdx.x * 128;
  const int rg = tid >> 4;   // 16 row groups of 8 rows
  const int cg = tid & 15;   // 16 col groups of 8 cols
  float acc[8][8];
#pragma unroll
  for (int i = 0; i < 8; ++i)
#pragma unroll
    for (int j = 0; j < 8; ++j) acc[i][j] = 0.f;

  for (int k0 = 0; k0 < 256; k0 += 64) {
#pragma unroll
    for (int i = 0; i < 8; ++i) {
      int idx = tid + i * 256;
      int r = idx >> 4;
      int kk = (idx & 15) << 2;
      int row = bm + r;
      float4 v = make_float4(0.f, 0.f, 0.f, 0.f);
      if (row < M) v = *(const float4*)&X[(size_t)row * 256 + k0 + kk];
      *(float4*)&xs[r][kk] = v;
    }
#pragma unroll
    for (int i = 0; i < 8; ++i) {
      int idx = tid + i * 256;
      int r = idx >> 5;
      int c = (idx & 31) << 2;
      *(float4*)&ws[r][c] = *(const float4*)&W[(size_t)(k0 + r) * 128 + c];
    }
    __syncthreads();
#pragma unroll
    for (int k4 = 0; k4 < 64; k4 += 4) {
      float4 xv[8];
#pragma unroll
      for (int r = 0; r < 8; ++r) xv[r] = *(const float4*)&xs[rg * 8 + r][k4];
#pragma unroll
      for (int kk = 0; kk < 4; ++kk) {
        float4 wa = *(const float4*)&ws[k4 + kk][cg * 8];
        float4 wb = *(const float4*)&ws[k4 + kk][cg * 8 + 4];
#pragma unroll
        for (int r = 0; r < 8; ++r) {
          float xx = (&xv[r].x)[kk];
          acc[r][0] = fmaf(xx, wa.x, acc[r][0]);
          acc[r][1] = fmaf(xx, wa.y, acc[r][1]);
          acc[r][2] = fmaf(xx, wa.z, acc[r][2]);
          acc[r][3] = fmaf(xx, wa.w, acc[r][3]);
          acc[r][4] = fmaf(xx, wb.x, acc[r][4]);
          acc[r][5] = fmaf(xx, wb.y, acc[r][5]);
          acc[r][6] = fmaf(xx, wb.z, acc[r][6]);
          acc[r][7] = fmaf(xx, wb.w, acc[r][7]);
        }
      }
    }
    __syncthreads();
  }
#pragma unroll
  for (int r = 0; r < 8; ++r) {
    int row = bm + rg * 8 + r;
    if (row < M) {
      *(float4*)&Y[(size_t)row * 128 + cg * 8] =
          make_float4(acc[r][0], acc[r][1], acc[r][2], acc[r][3]);
      *(float4*)&Y[(size_t)row * 128 + cg * 8 + 4] =
          make_float4(acc[r][4], acc[r][5], acc[r][6], acc[r][7]);
    }
  }
}

// -------- GEMM2: Y[M,64] = relu(H[M,128] + b1) @ W[128,64] (bias fused on load) --------
__global__ __launch_bounds__(256) void gemm2_k(const float* __restrict__ H,
                                               const float* __restrict__ b1,
                                               const float* __restrict__ W,
                                               float* __restrict__ Y, int M) {
  __shared__ float xs[128][64];
  __shared__ float ws[64][64];
  const int tid = threadIdx.x;
  const int bm = blockIdx.x * 128;
  const int rg = tid >> 4;
  const int cg = tid & 15;
  float acc[8][4];
#pragma unroll
  for (int i = 0; i < 8; ++i)
#pragma unroll
    for (int j = 0; j < 4; ++j) acc[i][j] = 0.f;

  for (int k0 = 0; k0 < 128; k0 += 64) {
#pragma unroll
    for (int i = 0; i < 8; ++i) {
      int idx = tid + i * 256;
      int r = idx >> 4;
      int kk = (idx & 15) << 2;
      int row = bm + r;
      float4 v = make_float4(0.f, 0.f, 0.f, 0.f);
      if (row < M) {
        v = *(const float4*)&H[(size_t)row * 128 + k0 + kk];
        float4 b = *(const float4*)&b1[k0 + kk];
        v.x = fmaxf(v.x + b.x, 0.f);
        v.y = fmaxf(v.y + b.y, 0.f);
        v.z = fmaxf(v.z + b.z, 0.f);
        v.w = fmaxf(v.w + b.w, 0.f);
      }
      *(float4*)&xs[r][kk] = v;
    }
#pragma unroll
    for (int i = 0; i < 4; ++i) {
      int idx = tid + i * 256;
      int r = idx >> 4;
      int c = (idx & 15) << 2;
      *(float4*)&ws[r][c] = *(const float4*)&W[(size_t)(k0 + r) * 64 + c];
    }
    __syncthreads();
#pragma unroll
    for (int k4 = 0; k4 < 64; k4 += 4) {
      float4 xv[8];
#pragma unroll
      for (int r = 0; r < 8; ++r) xv[r] = *(const float4*)&xs[rg * 8 + r][k4];
#pragma unroll
      for (int kk = 0; kk < 4; ++kk) {
        float4 wa = *(const float4*)&ws[k4 + kk][cg * 4];
#pragma unroll
        for (int r = 0; r < 8; ++r) {
          float xx = (&xv[r].x)[kk];
          acc[r][0] = fmaf(xx, wa.x, acc[r][0]);
          acc[r][1] = fmaf(xx, wa.y, acc[r][1]);
          acc[r][2] = fmaf(xx, wa.z, acc[r][2]);
          acc[r][3] = fmaf(xx, wa.w, acc[r][3]);
        }
      }
    }
    __syncthreads();
  }
#pragma unroll
  for (int r = 0; r < 8; ++r) {
    int row = bm + rg * 8 + r;
    if (row < M)
      *(float4*)&Y[(size_t)row * 64 + cg * 4] =
          make_float4(acc[r][0], acc[r][1], acc[r][2], acc[r][3]);
  }
}

// ---------------- CSR build ----------------
__global__ __launch_bounds__(256) void hist_k(const int* __restrict__ dst,
                                              int* __restrict__ deg, int E) {
  int i = blockIdx.x * 256 + threadIdx.x;
  if (i < E) atomicAdd(&deg[dst[i]], 1);
}

__global__ __launch_bounds__(256) void scan1_k(const int* __restrict__ deg,
                                               int* __restrict__ rowptr,
                                               int* __restrict__ partial, int M) {
  __shared__ int sh[256];
  int tid = threadIdx.x;
  int i = blockIdx.x * 256 + tid;
  int v = (i < M) ? deg[i] : 0;
  sh[tid] = v;
  __syncthreads();
#pragma unroll
  for (int o = 1; o < 256; o <<= 1) {
    int t = (tid >= o) ? sh[tid - o] : 0;
    __syncthreads();
    sh[tid] += t;
    __syncthreads();
  }
  if (i < M) rowptr[i] = sh[tid] - v;   // exclusive
  if (tid == 255) partial[blockIdx.x] = sh[255];
}

__global__ __launch_bounds__(512) void scan2_k(int* __restrict__ partial, int NB) {
  __shared__ int sh[512];
  int tid = threadIdx.x;
  int v = (tid < NB) ? partial[tid] : 0;
  sh[tid] = v;
  __syncthreads();
#pragma unroll
  for (int o = 1; o < 512; o <<= 1) {
    int t = (tid >= o) ? sh[tid - o] : 0;
    __syncthreads();
    sh[tid] += t;
    __syncthreads();
  }
  if (tid < NB) partial[tid] = sh[tid] - v;  // exclusive
}

__global__ __launch_bounds__(256) void scan3_k(int* __restrict__ rowptr,
                                               const int* __restrict__ partial,
                                               int* __restrict__ cursor, int M, int E) {
  int i = blockIdx.x * 256 + threadIdx.x;
  if (i < M) {
    int r = rowptr[i] + partial[i >> 8];
    rowptr[i] = r;
    cursor[i] = r;
    if (i == 0) rowptr[M] = E;
  }
}

__global__ __launch_bounds__(256) void scatter_k(const int* __restrict__ src,
                                                 const int* __restrict__ dst,
                                                 const float* __restrict__ vals,
                                                 int* __restrict__ cursor,
                                                 int2* __restrict__ edges, int E) {
  int i = blockIdx.x * 256 + threadIdx.x;
  if (i < E) {
    int pos = atomicAdd(&cursor[dst[i]], 1);
    int2 e;
    e.x = src[i];
    e.y = __float_as_int(vals[i]);
    edges[pos] = e;
  }
}

// ---------------- SpMM via CSR gather-reduce ----------------
// TPN threads per node, each owns a float4 column slice; C = TPN*4 columns.
template <int TPN, int C>
__global__ __launch_bounds__(256) void spmm_csr_k(const int* __restrict__ rowptr,
                                                  const int2* __restrict__ edges,
                                                  const float* __restrict__ X,
                                                  float* __restrict__ out, int M) {
  int node = blockIdx.x * (256 / TPN) + threadIdx.x / TPN;
  int g = (threadIdx.x % TPN) * 4;
  if (node >= M) return;
  int e = rowptr[node];
  const int end = rowptr[node + 1];
  float4 a0 = make_float4(0.f, 0.f, 0.f, 0.f);
  float4 a1 = make_float4(0.f, 0.f, 0.f, 0.f);
  for (; e + 2 <= end; e += 2) {
    int2 e0 = edges[e];
    int2 e1 = edges[e + 1];
    float v0 = __int_as_float(e0.y);
    float v1 = __int_as_float(e1.y);
    float4 x0 = *(const float4*)&X[(size_t)e0.x * C + g];
    float4 x1 = *(const float4*)&X[(size_t)e1.x * C + g];
    a0.x = fmaf(v0, x0.x, a0.x);
    a0.y = fmaf(v0, x0.y, a0.y);
    a0.z = fmaf(v0, x0.z, a0.z);
    a0.w = fmaf(v0, x0.w, a0.w);
    a1.x = fmaf(v1, x1.x, a1.x);
    a1.y = fmaf(v1, x1.y, a1.y);
    a1.z = fmaf(v1, x1.z, a1.z);
    a1.w = fmaf(v1, x1.w, a1.w);
  }
  if (e < end) {
    int2 e0 = edges[e];
    float v0 = __int_as_float(e0.y);
    float4 x0 = *(const float4*)&X[(size_t)e0.x * C + g];
    a0.x = fmaf(v0, x0.x, a0.x);
    a0.y = fmaf(v0, x0.y, a0.y);
    a0.z = fmaf(v0, x0.z, a0.z);
    a0.w = fmaf(v0, x0.w, a0.w);
  }
  a0.x += a1.x; a0.y += a1.y; a0.z += a1.z; a0.w += a1.w;
  *(float4*)&out[(size_t)node * C + g] = a0;
}

// ---------------- log_softmax over rows of 64, bias fused ----------------
__global__ __launch_bounds__(256) void lsm_k(const float* __restrict__ A,
                                             const float* __restrict__ b2,
                                             float* __restrict__ out, int M) {
  int row = blockIdx.x * 4 + (threadIdx.x >> 6);
  int lane = threadIdx.x & 63;
  if (row >= M) return;
  float v = A[(size_t)row * 64 + lane] + b2[lane];
  float m = v;
#pragma unroll
  for (int o = 32; o > 0; o >>= 1) m = fmaxf(m, __shfl_xor(m, o, 64));
  float e = expf(v - m);
  float s = e;
#pragma unroll
  for (int o = 32; o > 0; o >>= 1) s += __shfl_xor(s, o, 64);
  out[(size_t)row * 64 + lane] = v - m - logf(s);
}

extern "C" void kernel_launch(void* const* d_in, const int* in_sizes, int n_in,
                              void* d_out, int out_size, void* d_ws, size_t ws_size,
                              hipStream_t stream) {
  const float* x    = (const float*)d_in[0];
  const int*   src  = (const int*)  d_in[1];
  const int*   dst  = (const int*)  d_in[2];
  const float* vals = (const float*)d_in[3];
  const float* W1   = (const float*)d_in[4];
  const float* b1   = (const float*)d_in[5];
  const float* W2   = (const float*)d_in[6];
  const float* b2   = (const float*)d_in[7];
  const int M = in_sizes[0] / 256;   // 100000
  const int E = in_sizes[1];         // 1600000

  // workspace layout
  float* xw   = (float*)d_ws;                       // M*128
  float* hacc = xw + (size_t)M * 128;               // M*128
  int* deg    = (int*)(hacc + (size_t)M * 128);     // M
  int* rowptr = deg + M;                            // M+1
  int* cursor = rowptr + M + 1;                     // M
  int* partial = cursor + M;                        // 512
  int2* edges = (int2*)(((uintptr_t)(partial + 512) + 7) & ~(uintptr_t)7);  // E int2
  float* hw   = xw;                                 // M*64 (xw dead after spmm1)
  float* o2   = xw + (size_t)M * 64;                // M*64
  float* outf = (float*)d_out;

  const int NB = (M + 255) / 256;   // scan blocks (391)
  const int gb = (M + 127) / 128;
  const int ge = (E + 255) / 256;

  // --- CSR build (shared by both spmm layers) ---
  hipMemsetAsync(deg, 0, (size_t)M * sizeof(int), stream);
  hist_k<<<ge, 256, 0, stream>>>(dst, deg, E);
  scan1_k<<<NB, 256, 0, stream>>>(deg, rowptr, partial, M);
  scan2_k<<<1, 512, 0, stream>>>(partial, NB);
  scan3_k<<<NB, 256, 0, stream>>>(rowptr, partial, cursor, M, E);
  scatter_k<<<ge, 256, 0, stream>>>(src, dst, vals, cursor, edges, E);

  // --- layer 1 ---
  gemm1_k<<<gb, 256, 0, stream>>>(x, W1, xw, M);
  spmm_csr_k<32, 128><<<(M + 7) / 8, 256, 0, stream>>>(rowptr, edges, xw, hacc, M);

  // --- layer 2 ---
  gemm2_k<<<gb, 256, 0, stream>>>(hacc, b1, W2, hw, M);
  spmm_csr_k<16, 64><<<(M + 15) / 16, 256, 0, stream>>>(rowptr, edges, hw, o2, M);

  lsm_k<<<(M + 3) / 4, 256, 0, stream>>>(o2, b2, outf, M);
}

// Round 3
// 459.878 us; speedup vs baseline: 9.2788x; 1.2765x over previous
//
#include <hip/hip_runtime.h>
#include <stdint.h>

// GCN 2-layer forward.
// CSR build (hist/scan/scatter) -> gemm1(bf16 MFMA) -> spmm_csr
//   -> gemm2(bf16 MFMA, fused relu+b1) -> spmm_csr -> log_softmax(+b2)

typedef __attribute__((ext_vector_type(8))) short short8;
typedef __attribute__((ext_vector_type(4))) float f32x4;

// f32 -> bf16 bits (RNE), in low 16 of uint
static __device__ __forceinline__ uint32_t f2bu(float f) {
  uint32_t u = __float_as_uint(f);
  return (u + 0x7FFFu + ((u >> 16) & 1u)) >> 16;
}

// ---------------- weight prep: convert + transpose to bf16 ----------------
__global__ __launch_bounds__(256) void prepw_k(const float* __restrict__ W1,
                                               const float* __restrict__ W2,
                                               short* __restrict__ W1bt,
                                               short* __restrict__ W2bt) {
  int i = blockIdx.x * 256 + threadIdx.x;
  if (i < 256 * 128) {
    int k = i >> 7, c = i & 127;
    W1bt[c * 256 + k] = (short)f2bu(W1[i]);
  }
  if (i < 128 * 64) {
    int k = i >> 6, c = i & 63;
    W2bt[c * 128 + k] = (short)f2bu(W2[i]);
  }
}

// ---------------- GEMM1: Y[M,128] = X[M,256] @ W1, bf16 MFMA ----------------
// block: 256 thr = 4 waves (2x2), each wave 64x64 out. A staged LDS bf16, B from global.
__global__ __launch_bounds__(256) void gemm1_k(const float* __restrict__ X,
                                               const short* __restrict__ W1bt,
                                               float* __restrict__ Y, int M) {
  __shared__ short As[128][72];   // 18.4 KB, +8 pad -> 144B row stride
  const int tid = threadIdx.x;
  const int lane = tid & 63;
  const int wid = tid >> 6;
  const int wr = wid >> 1, wc = wid & 1;
  const int bm = blockIdx.x * 128;

  f32x4 acc[4][4];
#pragma unroll
  for (int i = 0; i < 4; ++i)
#pragma unroll
    for (int j = 0; j < 4; ++j) acc[i][j] = (f32x4)0.f;

  const int l15 = lane & 15;
  const int lk8 = (lane >> 4) * 8;

  for (int k0 = 0; k0 < 256; k0 += 64) {
    // stage A: 128 rows x 64 k, f32 -> bf16
#pragma unroll
    for (int i = 0; i < 8; ++i) {
      int idx = tid + i * 256;
      int r = idx >> 4;
      int kq = (idx & 15) << 2;
      int row = bm + r;
      float4 v = make_float4(0.f, 0.f, 0.f, 0.f);
      if (row < M) v = *(const float4*)&X[(size_t)row * 256 + k0 + kq];
      uint2 p;
      p.x = f2bu(v.x) | (f2bu(v.y) << 16);
      p.y = f2bu(v.z) | (f2bu(v.w) << 16);
      *(uint2*)&As[r][kq] = p;
    }
    __syncthreads();
#pragma unroll
    for (int kk = 0; kk < 64; kk += 32) {
      short8 a[4], b[4];
#pragma unroll
      for (int mi = 0; mi < 4; ++mi)
        a[mi] = *(const short8*)&As[wr * 64 + mi * 16 + l15][kk + lk8];
#pragma unroll
      for (int ni = 0; ni < 4; ++ni) {
        int bcol = wc * 64 + ni * 16 + l15;
        b[ni] = *(const short8*)&W1bt[bcol * 256 + k0 + kk + lk8];
      }
#pragma unroll
      for (int mi = 0; mi < 4; ++mi)
#pragma unroll
        for (int ni = 0; ni < 4; ++ni)
          acc[mi][ni] = __builtin_amdgcn_mfma_f32_16x16x32_bf16(a[mi], b[ni], acc[mi][ni], 0, 0, 0);
    }
    __syncthreads();
  }
  // epilogue: col=lane&15, row=(lane>>4)*4+reg
#pragma unroll
  for (int mi = 0; mi < 4; ++mi) {
    int rbase = bm + wr * 64 + mi * 16 + (lane >> 4) * 4;
#pragma unroll
    for (int j = 0; j < 4; ++j) {
      int row = rbase + j;
      if (row < M) {
#pragma unroll
        for (int ni = 0; ni < 4; ++ni)
          Y[(size_t)row * 128 + wc * 64 + ni * 16 + l15] = acc[mi][ni][j];
      }
    }
  }
}

// -------- GEMM2: Y[M,64] = relu(H+b1) @ W2, bf16 MFMA, bias/relu fused on stage --------
__global__ __launch_bounds__(256) void gemm2_k(const float* __restrict__ H,
                                               const float* __restrict__ b1,
                                               const short* __restrict__ W2bt,
                                               float* __restrict__ Y, int M) {
  __shared__ short As[128][72];
  const int tid = threadIdx.x;
  const int lane = tid & 63;
  const int wid = tid >> 6;          // wave owns rows wid*32..+32, all 64 cols
  const int bm = blockIdx.x * 128;

  f32x4 acc[2][4];
#pragma unroll
  for (int i = 0; i < 2; ++i)
#pragma unroll
    for (int j = 0; j < 4; ++j) acc[i][j] = (f32x4)0.f;

  const int l15 = lane & 15;
  const int lk8 = (lane >> 4) * 8;

  for (int k0 = 0; k0 < 128; k0 += 64) {
#pragma unroll
    for (int i = 0; i < 8; ++i) {
      int idx = tid + i * 256;
      int r = idx >> 4;
      int kq = (idx & 15) << 2;
      int row = bm + r;
      float4 v = make_float4(0.f, 0.f, 0.f, 0.f);
      if (row < M) {
        v = *(const float4*)&H[(size_t)row * 128 + k0 + kq];
        float4 bb = *(const float4*)&b1[k0 + kq];
        v.x = fmaxf(v.x + bb.x, 0.f);
        v.y = fmaxf(v.y + bb.y, 0.f);
        v.z = fmaxf(v.z + bb.z, 0.f);
        v.w = fmaxf(v.w + bb.w, 0.f);
      }
      uint2 p;
      p.x = f2bu(v.x) | (f2bu(v.y) << 16);
      p.y = f2bu(v.z) | (f2bu(v.w) << 16);
      *(uint2*)&As[r][kq] = p;
    }
    __syncthreads();
#pragma unroll
    for (int kk = 0; kk < 64; kk += 32) {
      short8 a[2], b[4];
#pragma unroll
      for (int mi = 0; mi < 2; ++mi)
        a[mi] = *(const short8*)&As[wid * 32 + mi * 16 + l15][kk + lk8];
#pragma unroll
      for (int ni = 0; ni < 4; ++ni)
        b[ni] = *(const short8*)&W2bt[(ni * 16 + l15) * 128 + k0 + kk + lk8];
#pragma unroll
      for (int mi = 0; mi < 2; ++mi)
#pragma unroll
        for (int ni = 0; ni < 4; ++ni)
          acc[mi][ni] = __builtin_amdgcn_mfma_f32_16x16x32_bf16(a[mi], b[ni], acc[mi][ni], 0, 0, 0);
    }
    __syncthreads();
  }
#pragma unroll
  for (int mi = 0; mi < 2; ++mi) {
    int rbase = bm + wid * 32 + mi * 16 + (lane >> 4) * 4;
#pragma unroll
    for (int j = 0; j < 4; ++j) {
      int row = rbase + j;
      if (row < M) {
#pragma unroll
        for (int ni = 0; ni < 4; ++ni)
          Y[(size_t)row * 64 + ni * 16 + l15] = acc[mi][ni][j];
      }
    }
  }
}

// ---------------- CSR build ----------------
__global__ __launch_bounds__(256) void hist_k(const int* __restrict__ dst,
                                              int* __restrict__ deg, int E) {
  int i = blockIdx.x * 256 + threadIdx.x;
  if (i < E) atomicAdd(&deg[dst[i]], 1);
}

__global__ __launch_bounds__(256) void scan1_k(const int* __restrict__ deg,
                                               int* __restrict__ rowptr,
                                               int* __restrict__ partial, int M) {
  __shared__ int sh[256];
  int tid = threadIdx.x;
  int i = blockIdx.x * 256 + tid;
  int v = (i < M) ? deg[i] : 0;
  sh[tid] = v;
  __syncthreads();
#pragma unroll
  for (int o = 1; o < 256; o <<= 1) {
    int t = (tid >= o) ? sh[tid - o] : 0;
    __syncthreads();
    sh[tid] += t;
    __syncthreads();
  }
  if (i < M) rowptr[i] = sh[tid] - v;   // exclusive
  if (tid == 255) partial[blockIdx.x] = sh[255];
}

__global__ __launch_bounds__(512) void scan2_k(int* __restrict__ partial, int NB) {
  __shared__ int sh[512];
  int tid = threadIdx.x;
  int v = (tid < NB) ? partial[tid] : 0;
  sh[tid] = v;
  __syncthreads();
#pragma unroll
  for (int o = 1; o < 512; o <<= 1) {
    int t = (tid >= o) ? sh[tid - o] : 0;
    __syncthreads();
    sh[tid] += t;
    __syncthreads();
  }
  if (tid < NB) partial[tid] = sh[tid] - v;  // exclusive
}

__global__ __launch_bounds__(256) void scan3_k(int* __restrict__ rowptr,
                                               const int* __restrict__ partial,
                                               int* __restrict__ cursor, int M, int E) {
  int i = blockIdx.x * 256 + threadIdx.x;
  if (i < M) {
    int r = rowptr[i] + partial[i >> 8];
    rowptr[i] = r;
    cursor[i] = r;
    if (i == 0) rowptr[M] = E;
  }
}

__global__ __launch_bounds__(256) void scatter_k(const int* __restrict__ src,
                                                 const int* __restrict__ dst,
                                                 const float* __restrict__ vals,
                                                 int* __restrict__ cursor,
                                                 int2* __restrict__ edges, int E) {
  int i = blockIdx.x * 256 + threadIdx.x;
  if (i < E) {
    int pos = atomicAdd(&cursor[dst[i]], 1);
    int2 e;
    e.x = src[i];
    e.y = __float_as_int(vals[i]);
    edges[pos] = e;
  }
}

// ---------------- SpMM via CSR gather-reduce ----------------
template <int TPN, int C>
__global__ __launch_bounds__(256) void spmm_csr_k(const int* __restrict__ rowptr,
                                                  const int2* __restrict__ edges,
                                                  const float* __restrict__ X,
                                                  float* __restrict__ out, int M) {
  int node = blockIdx.x * (256 / TPN) + threadIdx.x / TPN;
  int g = (threadIdx.x % TPN) * 4;
  if (node >= M) return;
  int e = rowptr[node];
  const int end = rowptr[node + 1];
  float4 a0 = make_float4(0.f, 0.f, 0.f, 0.f);
  float4 a1 = make_float4(0.f, 0.f, 0.f, 0.f);
  for (; e + 2 <= end; e += 2) {
    int2 e0 = edges[e];
    int2 e1 = edges[e + 1];
    float v0 = __int_as_float(e0.y);
    float v1 = __int_as_float(e1.y);
    float4 x0 = *(const float4*)&X[(size_t)e0.x * C + g];
    float4 x1 = *(const float4*)&X[(size_t)e1.x * C + g];
    a0.x = fmaf(v0, x0.x, a0.x);
    a0.y = fmaf(v0, x0.y, a0.y);
    a0.z = fmaf(v0, x0.z, a0.z);
    a0.w = fmaf(v0, x0.w, a0.w);
    a1.x = fmaf(v1, x1.x, a1.x);
    a1.y = fmaf(v1, x1.y, a1.y);
    a1.z = fmaf(v1, x1.z, a1.z);
    a1.w = fmaf(v1, x1.w, a1.w);
  }
  if (e < end) {
    int2 e0 = edges[e];
    float v0 = __int_as_float(e0.y);
    float4 x0 = *(const float4*)&X[(size_t)e0.x * C + g];
    a0.x = fmaf(v0, x0.x, a0.x);
    a0.y = fmaf(v0, x0.y, a0.y);
    a0.z = fmaf(v0, x0.z, a0.z);
    a0.w = fmaf(v0, x0.w, a0.w);
  }
  a0.x += a1.x; a0.y += a1.y; a0.z += a1.z; a0.w += a1.w;
  *(float4*)&out[(size_t)node * C + g] = a0;
}

// ---------------- log_softmax over rows of 64, bias fused ----------------
__global__ __launch_bounds__(256) void lsm_k(const float* __restrict__ A,
                                             const float* __restrict__ b2,
                                             float* __restrict__ out, int M) {
  int row = blockIdx.x * 4 + (threadIdx.x >> 6);
  int lane = threadIdx.x & 63;
  if (row >= M) return;
  float v = A[(size_t)row * 64 + lane] + b2[lane];
  float m = v;
#pragma unroll
  for (int o = 32; o > 0; o >>= 1) m = fmaxf(m, __shfl_xor(m, o, 64));
  float e = expf(v - m);
  float s = e;
#pragma unroll
  for (int o = 32; o > 0; o >>= 1) s += __shfl_xor(s, o, 64);
  out[(size_t)row * 64 + lane] = v - m - logf(s);
}

extern "C" void kernel_launch(void* const* d_in, const int* in_sizes, int n_in,
                              void* d_out, int out_size, void* d_ws, size_t ws_size,
                              hipStream_t stream) {
  const float* x    = (const float*)d_in[0];
  const int*   src  = (const int*)  d_in[1];
  const int*   dst  = (const int*)  d_in[2];
  const float* vals = (const float*)d_in[3];
  const float* W1   = (const float*)d_in[4];
  const float* b1   = (const float*)d_in[5];
  const float* W2   = (const float*)d_in[6];
  const float* b2   = (const float*)d_in[7];
  const int M = in_sizes[0] / 256;   // 100000
  const int E = in_sizes[1];         // 1600000

  // workspace layout
  float* xw   = (float*)d_ws;                       // M*128
  float* hacc = xw + (size_t)M * 128;               // M*128
  int* deg    = (int*)(hacc + (size_t)M * 128);     // M
  int* rowptr = deg + M;                            // M+1
  int* cursor = rowptr + M + 1;                     // M
  int* partial = cursor + M;                        // 512
  int2* edges = (int2*)(((uintptr_t)(partial + 512) + 15) & ~(uintptr_t)15); // E int2
  short* W1bt = (short*)(edges + E);                // 256*128 (16B aligned)
  short* W2bt = W1bt + 256 * 128;                   // 128*64
  float* hw   = xw;                                 // M*64 (xw dead after spmm1)
  float* o2   = xw + (size_t)M * 64;                // M*64
  float* outf = (float*)d_out;

  const int NB = (M + 255) / 256;
  const int gb = (M + 127) / 128;
  const int ge = (E + 255) / 256;

  // --- CSR build + weight prep ---
  hipMemsetAsync(deg, 0, (size_t)M * sizeof(int), stream);
  prepw_k<<<128, 256, 0, stream>>>(W1, W2, W1bt, W2bt);
  hist_k<<<ge, 256, 0, stream>>>(dst, deg, E);
  scan1_k<<<NB, 256, 0, stream>>>(deg, rowptr, partial, M);
  scan2_k<<<1, 512, 0, stream>>>(partial, NB);
  scan3_k<<<NB, 256, 0, stream>>>(rowptr, partial, cursor, M, E);
  scatter_k<<<ge, 256, 0, stream>>>(src, dst, vals, cursor, edges, E);

  // --- layer 1 ---
  gemm1_k<<<gb, 256, 0, stream>>>(x, W1bt, xw, M);
  spmm_csr_k<32, 128><<<(M + 7) / 8, 256, 0, stream>>>(rowptr, edges, xw, hacc, M);

  // --- layer 2 ---
  gemm2_k<<<gb, 256, 0, stream>>>(hacc, b1, W2bt, hw, M);
  spmm_csr_k<16, 64><<<(M + 15) / 16, 256, 0, stream>>>(rowptr, edges, hw, o2, M);

  lsm_k<<<(M + 3) / 4, 256, 0, stream>>>(o2, b2, outf, M);
}

// Round 4
// 316.163 us; speedup vs baseline: 13.4965x; 1.4546x over previous
//
#include <hip/hip_runtime.h>
#include <stdint.h>

// GCN 2-layer forward.
// prepw -> hist(XCD-sliced) -> scan -> scatter(XCD-sliced)
//  -> gemm1(bf16 MFMA, bf16 out) -> spmm1(bf16 gather -> bf16)
//  -> gemm2(bf16 MFMA, fused relu+b1, bf16 out) -> spmm2+log_softmax fused (f32 out)

typedef __attribute__((ext_vector_type(8))) short short8;
typedef __attribute__((ext_vector_type(8))) unsigned short ushort8;
typedef __attribute__((ext_vector_type(4))) float f32x4;

#define NSLICE 8
#define CHUNK 8192

// f32 -> bf16 bits (RNE)
static __device__ __forceinline__ uint32_t f2bu(float f) {
  uint32_t u = __float_as_uint(f);
  return (u + 0x7FFFu + ((u >> 16) & 1u)) >> 16;
}
static __device__ __forceinline__ float bu2f(unsigned short u) {
  return __uint_as_float(((uint32_t)u) << 16);
}

// ---------------- weight prep: convert + transpose to bf16 ----------------
__global__ __launch_bounds__(256) void prepw_k(const float* __restrict__ W1,
                                               const float* __restrict__ W2,
                                               short* __restrict__ W1bt,
                                               short* __restrict__ W2bt) {
  int i = blockIdx.x * 256 + threadIdx.x;
  if (i < 256 * 128) {
    int k = i >> 7, c = i & 127;
    W1bt[c * 256 + k] = (short)f2bu(W1[i]);
  }
  if (i < 128 * 64) {
    int k = i >> 6, c = i & 63;
    W2bt[c * 128 + k] = (short)f2bu(W2[i]);
  }
}

// ---------------- GEMM1: xwb[M,128](bf16) = X[M,256] @ W1 ----------------
__global__ __launch_bounds__(256) void gemm1_k(const float* __restrict__ X,
                                               const short* __restrict__ W1bt,
                                               unsigned short* __restrict__ Yb, int M) {
  __shared__ short As[128][72];   // 144B row stride = 16*9 -> conflict-free 16B ops
  const int tid = threadIdx.x;
  const int lane = tid & 63;
  const int wid = tid >> 6;
  const int wr = wid >> 1, wc = wid & 1;
  const int bm = blockIdx.x * 128;

  f32x4 acc[4][4];
#pragma unroll
  for (int i = 0; i < 4; ++i)
#pragma unroll
    for (int j = 0; j < 4; ++j) acc[i][j] = (f32x4)0.f;

  const int l15 = lane & 15;
  const int lk8 = (lane >> 4) * 8;

  for (int k0 = 0; k0 < 256; k0 += 64) {
#pragma unroll
    for (int i = 0; i < 8; ++i) {
      int idx = tid + i * 256;
      int r = idx >> 4;
      int kq = (idx & 15) << 2;
      int row = bm + r;
      float4 v = make_float4(0.f, 0.f, 0.f, 0.f);
      if (row < M) v = *(const float4*)&X[(size_t)row * 256 + k0 + kq];
      uint2 p;
      p.x = f2bu(v.x) | (f2bu(v.y) << 16);
      p.y = f2bu(v.z) | (f2bu(v.w) << 16);
      *(uint2*)&As[r][kq] = p;
    }
    __syncthreads();
#pragma unroll
    for (int kk = 0; kk < 64; kk += 32) {
      short8 a[4], b[4];
#pragma unroll
      for (int mi = 0; mi < 4; ++mi)
        a[mi] = *(const short8*)&As[wr * 64 + mi * 16 + l15][kk + lk8];
#pragma unroll
      for (int ni = 0; ni < 4; ++ni) {
        int bcol = wc * 64 + ni * 16 + l15;
        b[ni] = *(const short8*)&W1bt[bcol * 256 + k0 + kk + lk8];
      }
#pragma unroll
      for (int mi = 0; mi < 4; ++mi)
#pragma unroll
        for (int ni = 0; ni < 4; ++ni)
          acc[mi][ni] = __builtin_amdgcn_mfma_f32_16x16x32_bf16(a[mi], b[ni], acc[mi][ni], 0, 0, 0);
    }
    __syncthreads();
  }
  // C/D: col=lane&15, row=(lane>>4)*4+reg
#pragma unroll
  for (int mi = 0; mi < 4; ++mi) {
    int rbase = bm + wr * 64 + mi * 16 + (lane >> 4) * 4;
#pragma unroll
    for (int j = 0; j < 4; ++j) {
      int row = rbase + j;
      if (row < M) {
#pragma unroll
        for (int ni = 0; ni < 4; ++ni)
          Yb[(size_t)row * 128 + wc * 64 + ni * 16 + l15] =
              (unsigned short)f2bu(acc[mi][ni][j]);
      }
    }
  }
}

// -------- GEMM2: hwb[M,64](bf16) = relu(Hb+b1) @ W2 --------
__global__ __launch_bounds__(256) void gemm2_k(const unsigned short* __restrict__ Hb,
                                               const float* __restrict__ b1,
                                               const short* __restrict__ W2bt,
                                               unsigned short* __restrict__ Yb, int M) {
  __shared__ short As[128][72];
  const int tid = threadIdx.x;
  const int lane = tid & 63;
  const int wid = tid >> 6;
  const int bm = blockIdx.x * 128;

  f32x4 acc[2][4];
#pragma unroll
  for (int i = 0; i < 2; ++i)
#pragma unroll
    for (int j = 0; j < 4; ++j) acc[i][j] = (f32x4)0.f;

  const int l15 = lane & 15;
  const int lk8 = (lane >> 4) * 8;

  for (int k0 = 0; k0 < 128; k0 += 64) {
    // stage: 128 rows x 64 k bf16, fused bias+relu (1024 chunks of 16B)
#pragma unroll
    for (int i = 0; i < 4; ++i) {
      int idx = tid + i * 256;
      int r = idx >> 3;
      int c8 = (idx & 7) * 8;
      int row = bm + r;
      uint4 p = make_uint4(0, 0, 0, 0);
      if (row < M) {
        ushort8 hv = *(const ushort8*)&Hb[(size_t)row * 128 + k0 + c8];
        float4 ba = *(const float4*)&b1[k0 + c8];
        float4 bb = *(const float4*)&b1[k0 + c8 + 4];
        float f0 = fmaxf(bu2f(hv[0]) + ba.x, 0.f);
        float f1 = fmaxf(bu2f(hv[1]) + ba.y, 0.f);
        float f2 = fmaxf(bu2f(hv[2]) + ba.z, 0.f);
        float f3 = fmaxf(bu2f(hv[3]) + ba.w, 0.f);
        float f4 = fmaxf(bu2f(hv[4]) + bb.x, 0.f);
        float f5 = fmaxf(bu2f(hv[5]) + bb.y, 0.f);
        float f6 = fmaxf(bu2f(hv[6]) + bb.z, 0.f);
        float f7 = fmaxf(bu2f(hv[7]) + bb.w, 0.f);
        p.x = f2bu(f0) | (f2bu(f1) << 16);
        p.y = f2bu(f2) | (f2bu(f3) << 16);
        p.z = f2bu(f4) | (f2bu(f5) << 16);
        p.w = f2bu(f6) | (f2bu(f7) << 16);
      }
      *(uint4*)&As[r][c8] = p;
    }
    __syncthreads();
#pragma unroll
    for (int kk = 0; kk < 64; kk += 32) {
      short8 a[2], b[4];
#pragma unroll
      for (int mi = 0; mi < 2; ++mi)
        a[mi] = *(const short8*)&As[wid * 32 + mi * 16 + l15][kk + lk8];
#pragma unroll
      for (int ni = 0; ni < 4; ++ni)
        b[ni] = *(const short8*)&W2bt[(ni * 16 + l15) * 128 + k0 + kk + lk8];
#pragma unroll
      for (int mi = 0; mi < 2; ++mi)
#pragma unroll
        for (int ni = 0; ni < 4; ++ni)
          acc[mi][ni] = __builtin_amdgcn_mfma_f32_16x16x32_bf16(a[mi], b[ni], acc[mi][ni], 0, 0, 0);
    }
    __syncthreads();
  }
#pragma unroll
  for (int mi = 0; mi < 2; ++mi) {
    int rbase = bm + wid * 32 + mi * 16 + (lane >> 4) * 4;
#pragma unroll
    for (int j = 0; j < 4; ++j) {
      int row = rbase + j;
      if (row < M) {
#pragma unroll
        for (int ni = 0; ni < 4; ++ni)
          Yb[(size_t)row * 64 + ni * 16 + l15] =
              (unsigned short)f2bu(acc[mi][ni][j]);
      }
    }
  }
}

// ---------------- CSR build (XCD-sliced) ----------------
__global__ __launch_bounds__(256) void hist_s_k(const int* __restrict__ dst,
                                                int* __restrict__ deg,
                                                int E, int NPS, int M) {
  int slice = blockIdx.x & (NSLICE - 1);
  int chunk = blockIdx.x >> 3;
  int lo = slice * NPS;
  int hi = min(lo + NPS, M);
  int beg = chunk * CHUNK;
  int end2 = min(beg + CHUNK, E);
  for (int i = beg + threadIdx.x; i < end2; i += 256) {
    int d = dst[i];
    if (d >= lo && d < hi) atomicAdd(&deg[d], 1);
  }
}

__global__ __launch_bounds__(256) void scan1_k(const int* __restrict__ deg,
                                               int* __restrict__ rowptr,
                                               int* __restrict__ partial, int M) {
  __shared__ int sh[256];
  int tid = threadIdx.x;
  int i = blockIdx.x * 256 + tid;
  int v = (i < M) ? deg[i] : 0;
  sh[tid] = v;
  __syncthreads();
#pragma unroll
  for (int o = 1; o < 256; o <<= 1) {
    int t = (tid >= o) ? sh[tid - o] : 0;
    __syncthreads();
    sh[tid] += t;
    __syncthreads();
  }
  if (i < M) rowptr[i] = sh[tid] - v;
  if (tid == 255) partial[blockIdx.x] = sh[255];
}

__global__ __launch_bounds__(512) void scan2_k(int* __restrict__ partial, int NB) {
  __shared__ int sh[512];
  int tid = threadIdx.x;
  int v = (tid < NB) ? partial[tid] : 0;
  sh[tid] = v;
  __syncthreads();
#pragma unroll
  for (int o = 1; o < 512; o <<= 1) {
    int t = (tid >= o) ? sh[tid - o] : 0;
    __syncthreads();
    sh[tid] += t;
    __syncthreads();
  }
  if (tid < NB) partial[tid] = sh[tid] - v;
}

__global__ __launch_bounds__(256) void scan3_k(int* __restrict__ rowptr,
                                               const int* __restrict__ partial,
                                               int* __restrict__ cursor, int M, int E) {
  int i = blockIdx.x * 256 + threadIdx.x;
  if (i < M) {
    int r = rowptr[i] + partial[i >> 8];
    rowptr[i] = r;
    cursor[i] = r;
    if (i == 0) rowptr[M] = E;
  }
}

__global__ __launch_bounds__(256) void scatter_s_k(const int* __restrict__ src,
                                                   const int* __restrict__ dst,
                                                   const float* __restrict__ vals,
                                                   int* __restrict__ cursor,
                                                   int2* __restrict__ edges,
                                                   int E, int NPS, int M) {
  int slice = blockIdx.x & (NSLICE - 1);
  int chunk = blockIdx.x >> 3;
  int lo = slice * NPS;
  int hi = min(lo + NPS, M);
  int beg = chunk * CHUNK;
  int end2 = min(beg + CHUNK, E);
  for (int i = beg + threadIdx.x; i < end2; i += 256) {
    int d = dst[i];
    int s = src[i];          // unconditional coalesced loads
    float v = vals[i];
    if (d >= lo && d < hi) {
      int pos = atomicAdd(&cursor[d], 1);
      int2 e;
      e.x = s;
      e.y = __float_as_int(v);
      edges[pos] = e;
    }
  }
}

// ---------------- SpMM1: haccb[M,128](bf16) = A @ xwb ----------------
// 16 threads per node, each owns 8 bf16 cols.
__global__ __launch_bounds__(256) void spmm1_k(const int* __restrict__ rowptr,
                                               const int2* __restrict__ edges,
                                               const unsigned short* __restrict__ Xb,
                                               unsigned short* __restrict__ outb, int M) {
  int node = blockIdx.x * 16 + (threadIdx.x >> 4);
  int g = (threadIdx.x & 15) * 8;
  if (node >= M) return;
  int e = rowptr[node];
  const int end = rowptr[node + 1];
  float a0[8], a1[8];
#pragma unroll
  for (int j = 0; j < 8; ++j) { a0[j] = 0.f; a1[j] = 0.f; }
  for (; e + 2 <= end; e += 2) {
    int2 e0 = edges[e];
    int2 e1 = edges[e + 1];
    float v0 = __int_as_float(e0.y);
    float v1 = __int_as_float(e1.y);
    ushort8 x0 = *(const ushort8*)&Xb[(size_t)e0.x * 128 + g];
    ushort8 x1 = *(const ushort8*)&Xb[(size_t)e1.x * 128 + g];
#pragma unroll
    for (int j = 0; j < 8; ++j) {
      a0[j] = fmaf(v0, bu2f(x0[j]), a0[j]);
      a1[j] = fmaf(v1, bu2f(x1[j]), a1[j]);
    }
  }
  if (e < end) {
    int2 e0 = edges[e];
    float v0 = __int_as_float(e0.y);
    ushort8 x0 = *(const ushort8*)&Xb[(size_t)e0.x * 128 + g];
#pragma unroll
    for (int j = 0; j < 8; ++j) a0[j] = fmaf(v0, bu2f(x0[j]), a0[j]);
  }
  ushort8 o;
#pragma unroll
  for (int j = 0; j < 8; ++j) o[j] = (unsigned short)f2bu(a0[j] + a1[j]);
  *(ushort8*)&outb[(size_t)node * 128 + g] = o;
}

// ---------------- SpMM2 + bias + log_softmax fused: out[M,64](f32) ----------------
// 8 threads per node, each owns 8 cols; softmax via shfl_xor within the 8-lane group.
__global__ __launch_bounds__(256) void spmm2_lsm_k(const int* __restrict__ rowptr,
                                                   const int2* __restrict__ edges,
                                                   const unsigned short* __restrict__ Hb,
                                                   const float* __restrict__ b2,
                                                   float* __restrict__ out, int M) {
  int node = blockIdx.x * 32 + (threadIdx.x >> 3);
  int g = (threadIdx.x & 7) * 8;
  if (node >= M) return;
  int e = rowptr[node];
  const int end = rowptr[node + 1];
  float a0[8], a1[8];
#pragma unroll
  for (int j = 0; j < 8; ++j) { a0[j] = 0.f; a1[j] = 0.f; }
  for (; e + 2 <= end; e += 2) {
    int2 e0 = edges[e];
    int2 e1 = edges[e + 1];
    float v0 = __int_as_float(e0.y);
    float v1 = __int_as_float(e1.y);
    ushort8 x0 = *(const ushort8*)&Hb[(size_t)e0.x * 64 + g];
    ushort8 x1 = *(const ushort8*)&Hb[(size_t)e1.x * 64 + g];
#pragma unroll
    for (int j = 0; j < 8; ++j) {
      a0[j] = fmaf(v0, bu2f(x0[j]), a0[j]);
      a1[j] = fmaf(v1, bu2f(x1[j]), a1[j]);
    }
  }
  if (e < end) {
    int2 e0 = edges[e];
    float v0 = __int_as_float(e0.y);
    ushort8 x0 = *(const ushort8*)&Hb[(size_t)e0.x * 64 + g];
#pragma unroll
    for (int j = 0; j < 8; ++j) a0[j] = fmaf(v0, bu2f(x0[j]), a0[j]);
  }
  float v[8];
  float4 ba = *(const float4*)&b2[g];
  float4 bb = *(const float4*)&b2[g + 4];
  v[0] = a0[0] + a1[0] + ba.x; v[1] = a0[1] + a1[1] + ba.y;
  v[2] = a0[2] + a1[2] + ba.z; v[3] = a0[3] + a1[3] + ba.w;
  v[4] = a0[4] + a1[4] + bb.x; v[5] = a0[5] + a1[5] + bb.y;
  v[6] = a0[6] + a1[6] + bb.z; v[7] = a0[7] + a1[7] + bb.w;
  float m = v[0];
#pragma unroll
  for (int j = 1; j < 8; ++j) m = fmaxf(m, v[j]);
#pragma unroll
  for (int o = 1; o < 8; o <<= 1) m = fmaxf(m, __shfl_xor(m, o, 64));
  float s = 0.f;
#pragma unroll
  for (int j = 0; j < 8; ++j) s += expf(v[j] - m);
#pragma unroll
  for (int o = 1; o < 8; o <<= 1) s += __shfl_xor(s, o, 64);
  float lse = m + logf(s);
  float4 r0 = make_float4(v[0] - lse, v[1] - lse, v[2] - lse, v[3] - lse);
  float4 r1 = make_float4(v[4] - lse, v[5] - lse, v[6] - lse, v[7] - lse);
  *(float4*)&out[(size_t)node * 64 + g] = r0;
  *(float4*)&out[(size_t)node * 64 + g + 4] = r1;
}

extern "C" void kernel_launch(void* const* d_in, const int* in_sizes, int n_in,
                              void* d_out, int out_size, void* d_ws, size_t ws_size,
                              hipStream_t stream) {
  const float* x    = (const float*)d_in[0];
  const int*   src  = (const int*)  d_in[1];
  const int*   dst  = (const int*)  d_in[2];
  const float* vals = (const float*)d_in[3];
  const float* W1   = (const float*)d_in[4];
  const float* b1   = (const float*)d_in[5];
  const float* W2   = (const float*)d_in[6];
  const float* b2   = (const float*)d_in[7];
  const int M = in_sizes[0] / 256;   // 100000
  const int E = in_sizes[1];         // 1600000

  // workspace layout
  int2* edges = (int2*)d_ws;                                 // E*8B
  unsigned short* xwb   = (unsigned short*)(edges + E);      // M*128 bf16
  unsigned short* haccb = xwb + (size_t)M * 128;             // M*128 bf16
  unsigned short* hwb   = haccb + (size_t)M * 128;           // M*64 bf16
  int* deg    = (int*)(hwb + (size_t)M * 64);                // M
  int* rowptr = deg + M;                                     // M+1
  int* cursor = rowptr + M + 1;                              // M
  int* partial = cursor + M;                                 // 512
  short* W1bt = (short*)(partial + 512);                     // 256*128
  short* W2bt = W1bt + 256 * 128;                            // 128*64
  float* outf = (float*)d_out;

  const int NPS = (M + NSLICE - 1) / NSLICE;
  const int NB  = (M + 255) / 256;
  const int gb  = (M + 127) / 128;
  const int gsl = NSLICE * ((E + CHUNK - 1) / CHUNK);

  // --- CSR build + weight prep ---
  hipMemsetAsync(deg, 0, (size_t)M * sizeof(int), stream);
  prepw_k<<<128, 256, 0, stream>>>(W1, W2, W1bt, W2bt);
  hist_s_k<<<gsl, 256, 0, stream>>>(dst, deg, E, NPS, M);
  scan1_k<<<NB, 256, 0, stream>>>(deg, rowptr, partial, M);
  scan2_k<<<1, 512, 0, stream>>>(partial, NB);
  scan3_k<<<NB, 256, 0, stream>>>(rowptr, partial, cursor, M, E);
  scatter_s_k<<<gsl, 256, 0, stream>>>(src, dst, vals, cursor, edges, E, NPS, M);

  // --- layer 1 ---
  gemm1_k<<<gb, 256, 0, stream>>>(x, W1bt, xwb, M);
  spmm1_k<<<(M + 15) / 16, 256, 0, stream>>>(rowptr, edges, xwb, haccb, M);

  // --- layer 2 + fused log_softmax ---
  gemm2_k<<<gb, 256, 0, stream>>>(haccb, b1, W2bt, hwb, M);
  spmm2_lsm_k<<<(M + 31) / 32, 256, 0, stream>>>(rowptr, edges, hwb, b2, outf, M);
}